// Round 22
// baseline (121.377 us; speedup 1.0000x reference)
//
#include <hip/hip_runtime.h>
#include <stdint.h>

#define IN_C   16
#define OUT_C  16
#define EDGE_DIM 8
#define HID    32
#define HSTR   20      // H LDS row stride in dwords
#define XSTR   20      // x LDS row stride in floats
#define MAXDEG 48      // per-node edge-id list capacity (max degree ~35 for E/N=16)
#define FEPB   128     // edges per block (both roles)
#define OVFCAP 65536

typedef __attribute__((ext_vector_type(8))) short short8v;  // bf16x8 MFMA frag
typedef __attribute__((ext_vector_type(4))) float f32x4;

__device__ __forceinline__ uint32_t pack_bf16(float a, float b) {
    union { float f; uint32_t u; } ua, ub;
    ua.f = a; ub.f = b;
    uint32_t lo = (ua.u + 0x7FFFu + ((ua.u >> 16) & 1u)) >> 16;   // RNE
    uint32_t hi = (ub.u + 0x7FFFu + ((ub.u >> 16) & 1u)) >> 16;
    return (lo & 0xFFFFu) | (hi << 16);
}

// blocks [0,4): pre-pack W2 into per-lane MFMA B-fragments (bf16).
// block 4: b2t[o*16+ci] = b2[ci*16+o].
// blocks [5,...): grid-stride zero of cur[N] + novf.
__global__ __launch_bounds__(256) void nnconv_prep(
    const float* __restrict__ W2, uint4* __restrict__ W2p,
    const float* __restrict__ b2, float* __restrict__ b2t,
    int* __restrict__ zero_base, int n_zero_ints)
{
    int bid = blockIdx.x;
    if (bid < 4) {
        int idx = bid * 256 + threadIdx.x;      // 0..1023 = ci*64 + l
        int ci = idx >> 6, l = idx & 63;
        int o = l & 15, g = l >> 4;
        uint32_t u[4];
        #pragma unroll
        for (int v = 0; v < 4; ++v) {
            int k0 = g * 8 + 2 * v;
            u[v] = pack_bf16(W2[(size_t)k0 * 256 + ci * 16 + o],
                             W2[(size_t)(k0 + 1) * 256 + ci * 16 + o]);
        }
        W2p[idx] = make_uint4(u[0], u[1], u[2], u[3]);
        return;
    }
    if (bid == 4) {
        int t = threadIdx.x;                     // t = o*16+ci
        b2t[t] = b2[(t & 15) * 16 + (t >> 4)];
        return;
    }
    int t = (bid - 5) * 256 + threadIdx.x;
    int stride = (gridDim.x - 5) * 256;
    for (int i = t; i < n_zero_ints; i += stride)
        zero_base[i] = 0;
}

// ============ TIER 1 main: interleaved roles ============
// odd blocks: RANK role — returning atomic builds per-node edge-id lists.
// even blocks: FUSED role — MLP+GEMM, msg stored at NATURAL edge index
// (deterministic address: no atomic, no shuffle, coalesced). The rank waves'
// atomic latency co-schedules with fused waves' compute on the same CUs.
__global__ __launch_bounds__(256, 2) void nnconv_main(
    const float* __restrict__ pseudo, const int* __restrict__ eidx,
    const float* __restrict__ x,
    const float* __restrict__ W1, const float* __restrict__ b1,
    const uint4* __restrict__ W2p, const float* __restrict__ b2t,
    int* __restrict__ cur, int* __restrict__ eid,
    int* __restrict__ ovfeid, int* __restrict__ novf,
    uint32_t* __restrict__ msgu, int n_edges)
{
    __shared__ uint32_t Hl[FEPB * HSTR];
    __shared__ float    xl[FEPB * XSTR];
    __shared__ uint4    Wl[1024];            // 16 KB block-shared B-fragments

    int t   = threadIdx.x;
    int bid = blockIdx.x;

    if (bid & 1) {
        // ---- RANK role ----
        int e2 = (bid >> 1) * FEPB + t;
        if (e2 < n_edges) {
            int r = eidx[e2];
            int rank = atomicAdd(&cur[r], 1);
            if (rank < MAXDEG) {
                eid[(size_t)r * MAXDEG + rank] = e2;
            } else {
                int pos = atomicAdd(novf, 1);
                if (pos < OVFCAP) ovfeid[pos] = e2;
            }
        }
        return;
    }

    // ---- FUSED role ----
    int e0 = (bid >> 1) * FEPB;
    int e  = e0 + t;
    bool valid = e < n_edges;
    int lane = t & 63, w = t >> 6;
    int o = lane & 15, g = lane >> 4;

    // stage: x + pseudo + b2t loads
    float p[EDGE_DIM];
    {
        float4* xd = reinterpret_cast<float4*>(&xl[t * XSTR]);
        if (valid) {
            int c = eidx[n_edges + e];
            const float4* xp = reinterpret_cast<const float4*>(x + (size_t)c * IN_C);
            xd[0] = xp[0]; xd[1] = xp[1]; xd[2] = xp[2]; xd[3] = xp[3];
            const float4* pp = reinterpret_cast<const float4*>(pseudo + (size_t)e * EDGE_DIM);
            float4 p0 = pp[0], p1 = pp[1];
            p[0]=p0.x; p[1]=p0.y; p[2]=p0.z; p[3]=p0.w;
            p[4]=p1.x; p[5]=p1.y; p[6]=p1.z; p[7]=p1.w;
        } else {
            float4 z = make_float4(0.f, 0.f, 0.f, 0.f);
            xd[0] = z; xd[1] = z; xd[2] = z; xd[3] = z;
            #pragma unroll
            for (int k = 0; k < EDGE_DIM; ++k) p[k] = 0.f;
        }
    }
    float b2v[16];
    {
        const float4* bp = reinterpret_cast<const float4*>(b2t + o * 16);
        #pragma unroll
        for (int c4 = 0; c4 < 4; ++c4) {
            float4 bv = bp[c4];
            b2v[c4*4+0] = bv.x; b2v[c4*4+1] = bv.y;
            b2v[c4*4+2] = bv.z; b2v[c4*4+3] = bv.w;
        }
    }

    // Wl copy: 4 chunks of 4 uint4 (16 VGPR in flight max)
    for (int ch = 0; ch < 4; ++ch) {
        uint4 c0 = W2p[lane + (ch * 4 + 0) * 64];
        uint4 c1 = W2p[lane + (ch * 4 + 1) * 64];
        uint4 c2 = W2p[lane + (ch * 4 + 2) * 64];
        uint4 c3 = W2p[lane + (ch * 4 + 3) * 64];
        Wl[lane + (ch * 4 + 0) * 64] = c0;
        Wl[lane + (ch * 4 + 1) * 64] = c1;
        Wl[lane + (ch * 4 + 2) * 64] = c2;
        Wl[lane + (ch * 4 + 3) * 64] = c3;
    }

    // MLP (k-outer: W1 rows contiguous -> wide wave-uniform scalar loads)
    {
        float h[HID];
        #pragma unroll
        for (int j = 0; j < HID; ++j) h[j] = b1[j];
        #pragma unroll
        for (int k = 0; k < EDGE_DIM; ++k) {
            float pk = p[k];
            const float* wr = W1 + k * HID;
            #pragma unroll
            for (int j = 0; j < HID; ++j)
                h[j] = fmaf(pk, wr[j], h[j]);
        }
        uint32_t hw[16];
        #pragma unroll
        for (int v = 0; v < 16; ++v) {
            float a0 = h[2*v]   > 0.f ? h[2*v]   : 0.f;
            float a1 = h[2*v+1] > 0.f ? h[2*v+1] : 0.f;
            hw[v] = valid ? pack_bf16(a0, a1) : 0u;
        }
        uint4* hp = reinterpret_cast<uint4*>(&Hl[t * HSTR]);
        hp[0] = make_uint4(hw[0],  hw[1],  hw[2],  hw[3]);
        hp[1] = make_uint4(hw[4],  hw[5],  hw[6],  hw[7]);
        hp[2] = make_uint4(hw[8],  hw[9],  hw[10], hw[11]);
        hp[3] = make_uint4(hw[12], hw[13], hw[14], hw[15]);
    }
    // no barrier: every wave reads only its own 64 rows of Hl/xl; Wl identical

    int ebase = w * 64;

    // GEMM: all operands from LDS/regs (q-outer, macc[4] live)
    #pragma unroll
    for (int q = 0; q < 4; ++q) {
        short8v A = *reinterpret_cast<const short8v*>(
            &Hl[(size_t)(ebase + q * 16 + o) * HSTR + g * 4]);
        float macc[4] = {0.f, 0.f, 0.f, 0.f};
        #pragma unroll
        for (int cq = 0; cq < 4; ++cq) {
            short8v Bf[4];
            #pragma unroll
            for (int j = 0; j < 4; ++j)
                Bf[j] = *reinterpret_cast<const short8v*>(&Wl[(cq * 4 + j) * 64 + lane]);
            f32x4 C[4];
            #pragma unroll
            for (int j = 0; j < 4; ++j) {
                float bb = b2v[cq * 4 + j];
                C[j] = __builtin_amdgcn_mfma_f32_16x16x32_bf16(
                    A, Bf[j], (f32x4){bb, bb, bb, bb}, 0, 0, 0);
            }
            #pragma unroll
            for (int r = 0; r < 4; ++r) {
                int el = ebase + q * 16 + g * 4 + r;
                float4 xa = *reinterpret_cast<const float4*>(&xl[el * XSTR + cq * 4]);
                float m = macc[r];
                m = fmaf(xa.x, C[0][r], m); m = fmaf(xa.y, C[1][r], m);
                m = fmaf(xa.z, C[2][r], m); m = fmaf(xa.w, C[3][r], m);
                macc[r] = m;
            }
        }
        // bf16 pair-pack; even-o lanes store dword (o>>1) of edge (e0+el):
        // natural order, deterministic, coalesced within the 512B window
        #pragma unroll
        for (int r = 0; r < 4; ++r) {
            int el = ebase + q * 16 + g * 4 + r;       // block-local edge row
            float other = __shfl_xor(macc[r], 1, 64);
            if (!(o & 1) && (e0 + el) < n_edges) {
                uint32_t dw = pack_bf16(macc[r], other);
                msgu[(size_t)(e0 + el) * 8 + (o >> 1)] = dw;
            }
        }
    }
}

// wave per node: out = bias + x@root + sum over eid-list msg rows
__global__ __launch_bounds__(256) void nnconv_gather1(
    const uint32_t* __restrict__ msgu, const int* __restrict__ cur,
    const int* __restrict__ eid, const float* __restrict__ x,
    const float* __restrict__ root, const float* __restrict__ bias,
    float* __restrict__ out, int n_nodes)
{
    int wave = threadIdx.x >> 6, lane = threadIdx.x & 63;
    int n = blockIdx.x * 4 + wave;
    if (n >= n_nodes) return;
    int group = lane >> 4, o = lane & 15;
    int craw = cur[n];
    int cntn = craw > MAXDEG ? MAXDEG : craw;
    const int* el = eid + (size_t)n * MAXDEG;
    float acc = 0.f;
    int half = o & 1;
    int dwi = o >> 1;
    for (int k = group; k < cntn; k += 4) {
        int e = el[k];                             // broadcast within group
        uint32_t u = msgu[(size_t)e * 8 + dwi];
        uint32_t h16 = half ? (u & 0xFFFF0000u) : (u << 16);
        union { uint32_t u; float f; } cv; cv.u = h16;
        acc += cv.f;
    }
    acc += __shfl_xor(acc, 16, 64);
    acc += __shfl_xor(acc, 32, 64);
    if (group == 0) {
        float r = bias[o];
        const float* xr = x + (size_t)n * IN_C;
        #pragma unroll
        for (int i = 0; i < IN_C; ++i)
            r = fmaf(xr[i], root[i * OUT_C + o], r);
        out[n * OUT_C + o] = r + acc;
    }
}

// post-gather: fold overflow edges (rank >= MAXDEG, ~never) into out via atomics
__global__ __launch_bounds__(256) void nnconv_ovf(
    const uint32_t* __restrict__ msgu, const int* __restrict__ ovfeid,
    const int* __restrict__ novf, const int* __restrict__ eidx,
    float* __restrict__ out, int n_edges)
{
    int cnt = *novf; if (cnt > OVFCAP) cnt = OVFCAP;
    int total = cnt * OUT_C;
    for (int i = blockIdx.x * 256 + threadIdx.x; i < total; i += gridDim.x * 256) {
        int idx = i >> 4, o = i & 15;
        int e = ovfeid[idx];
        int row = eidx[e];
        uint32_t u = msgu[(size_t)e * 8 + (o >> 1)];
        uint32_t h16 = (o & 1) ? (u & 0xFFFF0000u) : (u << 16);
        union { uint32_t u; float f; } cv; cv.u = h16;
        atomicAdd(&out[(size_t)row * OUT_C + o], cv.f);
    }
}

// ============ TIER 3: direct-atomic fallback ============

__global__ __launch_bounds__(256) void nnconv_init_out(
    const float* __restrict__ x, const float* __restrict__ root,
    const float* __restrict__ bias, float* __restrict__ out, int n_nodes)
{
    int t = blockIdx.x * blockDim.x + threadIdx.x;
    if (t >= n_nodes * OUT_C) return;
    int n = t >> 4, o = t & 15;
    float acc = bias[o];
    #pragma unroll
    for (int i = 0; i < IN_C; ++i)
        acc = fmaf(x[n * IN_C + i], root[i * OUT_C + o], acc);
    out[t] = acc;
}

__global__ __launch_bounds__(256) void nnconv_edge_atomic(
    const float* __restrict__ x, const int* __restrict__ edge_index,
    const float* __restrict__ pseudo,
    const float* __restrict__ W1, const float* __restrict__ b1,
    const float* __restrict__ W2, const float* __restrict__ b2,
    float* __restrict__ out, int n_edges)
{
    int e = blockIdx.x * blockDim.x + threadIdx.x;
    if (e >= n_edges) return;
    int row = edge_index[e];
    int col = edge_index[n_edges + e];
    float p[EDGE_DIM];
    const float4* pp = reinterpret_cast<const float4*>(pseudo + (size_t)e * EDGE_DIM);
    float4 p0 = pp[0], p1 = pp[1];
    p[0]=p0.x; p[1]=p0.y; p[2]=p0.z; p[3]=p0.w;
    p[4]=p1.x; p[5]=p1.y; p[6]=p1.z; p[7]=p1.w;
    float h[HID];
    #pragma unroll
    for (int j = 0; j < HID; ++j) {
        float a = b1[j];
        #pragma unroll
        for (int k = 0; k < EDGE_DIM; ++k)
            a = fmaf(p[k], W1[k * HID + j], a);
        h[j] = a > 0.f ? a : 0.f;
    }
    float xg[IN_C];
    const float4* xp = reinterpret_cast<const float4*>(x + (size_t)col * IN_C);
    #pragma unroll
    for (int q = 0; q < 4; ++q) {
        float4 v = xp[q];
        xg[q*4+0]=v.x; xg[q*4+1]=v.y; xg[q*4+2]=v.z; xg[q*4+3]=v.w;
    }
    float m[OUT_C];
    #pragma unroll
    for (int o = 0; o < OUT_C; ++o) m[o] = 0.f;
    for (int i = 0; i < IN_C; ++i) {
        float wv[OUT_C];
        const float* b2r = b2 + i * OUT_C;
        #pragma unroll
        for (int o = 0; o < OUT_C; ++o) wv[o] = b2r[o];
        #pragma unroll
        for (int j = 0; j < HID; ++j) {
            float hj = h[j];
            const float* wr = W2 + j * (IN_C * OUT_C) + i * OUT_C;
            #pragma unroll
            for (int o = 0; o < OUT_C; ++o)
                wv[o] = fmaf(hj, wr[o], wv[o]);
        }
        float xi = xg[i];
        #pragma unroll
        for (int o = 0; o < OUT_C; ++o)
            m[o] = fmaf(xi, wv[o], m[o]);
    }
    float* op = out + (size_t)row * OUT_C;
    #pragma unroll
    for (int o = 0; o < OUT_C; ++o)
        atomicAdd(op + o, m[o]);
}

// ---------------- launch ----------------

extern "C" void kernel_launch(void* const* d_in, const int* in_sizes, int n_in,
                              void* d_out, int out_size, void* d_ws, size_t ws_size,
                              hipStream_t stream) {
    const float* x      = (const float*)d_in[0];
    const int*   eidx   = (const int*)  d_in[1];
    const float* pseudo = (const float*)d_in[2];
    const float* W1     = (const float*)d_in[3];
    const float* b1     = (const float*)d_in[4];
    const float* W2     = (const float*)d_in[5];
    const float* b2     = (const float*)d_in[6];
    const float* root   = (const float*)d_in[7];
    const float* bias   = (const float*)d_in[8];
    float* out = (float*)d_out;

    int n_nodes = in_sizes[0] / IN_C;
    int n_edges = in_sizes[1] / 2;
    int eblocks128 = (n_edges + FEPB - 1) / FEPB;
    int eblocks256 = (n_edges + 255) / 256;
    size_t Epad = (size_t)eblocks128 * FEPB;
    char* wsp = (char*)d_ws;

    // tier 1 layout: cur[N] novf[64] ovfeid[OVFCAP] |256| W2p[1024 u4] b2t[256 f]
    //                |256| eid[N*MAXDEG int] |256| msgu[Epad*8 u32]
    {
        int* cur1   = (int*)wsp;
        int* novf   = cur1 + n_nodes;
        int* ovfeid = novf + 64;
        size_t off = sizeof(int) * ((size_t)n_nodes + 64 + OVFCAP);
        off = (off + 255) & ~(size_t)255;
        uint4* W2p = (uint4*)(wsp + off);
        off += sizeof(uint4) * 1024;
        float* b2t = (float*)(wsp + off);
        off += sizeof(float) * 256;
        off = (off + 255) & ~(size_t)255;
        int* eid = (int*)(wsp + off);
        off += sizeof(int) * (size_t)n_nodes * MAXDEG;
        off = (off + 255) & ~(size_t)255;
        uint32_t* msgu = (uint32_t*)(wsp + off);
        size_t need = off + sizeof(uint32_t) * Epad * 8;

        if (ws_size >= need) {
            int n_zero_ints = n_nodes + 64;   // cur + novf
            nnconv_prep<<<5 + 32, 256, 0, stream>>>(W2, W2p, b2, b2t, cur1, n_zero_ints);
            nnconv_main<<<2 * eblocks128, FEPB, 0, stream>>>(
                pseudo, eidx, x, W1, b1, W2p, b2t,
                cur1, eid, ovfeid, novf, msgu, n_edges);
            nnconv_gather1<<<(n_nodes + 3) / 4, 256, 0, stream>>>(
                msgu, cur1, eid, x, root, bias, out, n_nodes);
            nnconv_ovf<<<8, 256, 0, stream>>>(msgu, ovfeid, novf, eidx, out, n_edges);
            return;
        }
    }

    nnconv_init_out<<<(n_nodes * OUT_C + 255) / 256, 256, 0, stream>>>(
        x, root, bias, out, n_nodes);
    nnconv_edge_atomic<<<eblocks256, 256, 0, stream>>>(
        x, eidx, pseudo, W1, b1, W2, b2, out, n_edges);
}

// Round 23
// 121.274 us; speedup vs baseline: 1.0008x; 1.0008x over previous
//
#include <hip/hip_runtime.h>
#include <stdint.h>

#define IN_C   16
#define OUT_C  16
#define EDGE_DIM 8
#define HID    32
#define HSTR   20      // H LDS row stride in dwords
#define XSTR   20      // x LDS row stride in floats
#define FEPB   128     // edges per fused block (2 waves)
#define CHUNK  4096    // edges per rank-chunk (lrank < 4096 fits u16)
#define RPAD   32768   // padded row capacity (tier-1 requires n_nodes <= RPAD)
#define HDW    (RPAD/2) // hist dwords (2 packed u16 rows per dword) = 64KB LDS

typedef __attribute__((ext_vector_type(8))) short short8v;  // bf16x8 MFMA frag
typedef __attribute__((ext_vector_type(4))) float f32x4;

__device__ __forceinline__ uint32_t pack_bf16(float a, float b) {
    union { float f; uint32_t u; } ua, ub;
    ua.f = a; ub.f = b;
    uint32_t lo = (ua.u + 0x7FFFu + ((ua.u >> 16) & 1u)) >> 16;   // RNE
    uint32_t hi = (ub.u + 0x7FFFu + ((ub.u >> 16) & 1u)) >> 16;
    return (lo & 0xFFFFu) | (hi << 16);
}

// ============ kernel A: per-chunk LDS counting-sort ranks (+ W2 pack + b2t) ============
// blocks [0,K): chunk k -> lrank16[e] (rank within (chunk,row)) + histg[k][*]
// blocks [K,K+4): W2 pack; block K+4: b2t + zero total.
__global__ __launch_bounds__(256) void nnconv_rank(
    const int* __restrict__ eidx, uint16_t* __restrict__ lrank16,
    uint32_t* __restrict__ histg,
    const float* __restrict__ W2, uint4* __restrict__ W2p,
    const float* __restrict__ b2, float* __restrict__ b2t,
    int* __restrict__ total, int n_edges, int K)
{
    __shared__ uint32_t hist[HDW];          // 64 KB: packed u16 pair per dword
    int bid = blockIdx.x, t = threadIdx.x;

    if (bid >= K) {
        if (bid < K + 4) {
            int idx = (bid - K) * 256 + t;  // 0..1023 = ci*64 + l
            int ci = idx >> 6, l = idx & 63;
            int o = l & 15, g = l >> 4;
            uint32_t u[4];
            #pragma unroll
            for (int v = 0; v < 4; ++v) {
                int k0 = g * 8 + 2 * v;
                u[v] = pack_bf16(W2[(size_t)k0 * 256 + ci * 16 + o],
                                 W2[(size_t)(k0 + 1) * 256 + ci * 16 + o]);
            }
            W2p[idx] = make_uint4(u[0], u[1], u[2], u[3]);
        } else {
            b2t[t] = b2[(t & 15) * 16 + (t >> 4)];   // t = o*16+ci
            if (t == 0) *total = 0;
        }
        return;
    }

    for (int i = t; i < HDW; i += 256) hist[i] = 0;
    __syncthreads();

    int ebase = bid * CHUNK;
    #pragma unroll
    for (int it = 0; it < CHUNK / 256; ++it) {
        int e = ebase + it * 256 + t;
        if (e < n_edges) {
            int r = eidx[e];
            uint32_t inc = (r & 1) ? 0x10000u : 1u;
            uint32_t old = atomicAdd(&hist[r >> 1], inc);
            uint32_t lr = (r & 1) ? (old >> 16) : (old & 0xFFFFu);
            lrank16[e] = (uint16_t)lr;
        }
    }
    __syncthreads();

    uint32_t* hg = histg + (size_t)bid * HDW;
    for (int i = t; i < HDW; i += 256) hg[i] = hist[i];
}

// ============ kernel B: cross-chunk scan -> chunkbase[k][r], base[r], cnt[r] ============
// 16384 threads; thread rr owns rows (2rr, 2rr+1).
__global__ __launch_bounds__(256) void nnconv_scan(
    const uint32_t* __restrict__ histg, uint32_t* __restrict__ chunkbase,
    int* __restrict__ baseArr, int* __restrict__ cntArr,
    int* __restrict__ total, int K)
{
    int rr = blockIdx.x * 256 + threadIdx.x;     // 0..HDW-1
    int lane = threadIdx.x & 63;
    uint32_t sumlo = 0, sumhi = 0;
    for (int k = 0; k < K; ++k) {
        uint32_t u = histg[(size_t)k * HDW + rr];
        sumlo += u & 0xFFFFu;
        sumhi += u >> 16;
    }
    int comb = (int)(sumlo + sumhi);
    int s = comb;                                 // inclusive wave scan
    #pragma unroll
    for (int d = 1; d < 64; d <<= 1) {
        int v = __shfl_up(s, d, 64);
        if (lane >= d) s += v;
    }
    int wsum = __shfl(s, 63, 64);
    int wbase = 0;
    if (lane == 63) wbase = atomicAdd(total, wsum);
    wbase = __shfl(wbase, 63, 64);
    int myex = wbase + s - comb;
    int r0 = 2 * rr, r1 = 2 * rr + 1;
    int baselo = myex, basehi = myex + (int)sumlo;
    baseArr[r0] = baselo; baseArr[r1] = basehi;
    cntArr[r0]  = (int)sumlo; cntArr[r1] = (int)sumhi;
    uint32_t lo = (uint32_t)baselo, hi = (uint32_t)basehi;
    for (int k = 0; k < K; ++k) {
        uint32_t u = histg[(size_t)k * HDW + rr];
        chunkbase[(size_t)k * RPAD + r0] = lo;
        chunkbase[(size_t)k * RPAD + r1] = hi;
        lo += u & 0xFFFFu;
        hi += u >> 16;
    }
}

// ============ kernel C: fused MLP+GEMM, deterministic slots (NO atomics) ============
__global__ __launch_bounds__(256, 2) void nnconv_fused1(
    const float* __restrict__ pseudo, const int* __restrict__ eidx,
    const float* __restrict__ x,
    const float* __restrict__ W1, const float* __restrict__ b1,
    const uint4* __restrict__ W2p, const float* __restrict__ b2t,
    const uint32_t* __restrict__ chunkbase, const uint16_t* __restrict__ lrank16,
    uint32_t* __restrict__ msgu, int n_edges)
{
    __shared__ uint32_t Hl[FEPB * HSTR];
    __shared__ float    xl[FEPB * XSTR];
    __shared__ uint4    Wl[1024];            // 16 KB block-shared B-fragments

    int t  = threadIdx.x;
    int e0 = blockIdx.x * FEPB;
    int e  = e0 + t;
    bool valid = e < n_edges;
    int lane = t & 63, w = t >> 6;
    int o = lane & 15, g = lane >> 4;
    int kch = e0 / CHUNK;                    // uniform per block (CHUNK % FEPB == 0)

    // ---- stage: slot (2 loads, no atomic) + x + pseudo ----
    int slv = -1;
    float p[EDGE_DIM];
    {
        float4* xd = reinterpret_cast<float4*>(&xl[t * XSTR]);
        if (valid) {
            int r = eidx[e];
            slv = (int)chunkbase[(size_t)kch * RPAD + r] + (int)lrank16[e];
            int c = eidx[n_edges + e];
            const float4* xp = reinterpret_cast<const float4*>(x + (size_t)c * IN_C);
            xd[0] = xp[0]; xd[1] = xp[1]; xd[2] = xp[2]; xd[3] = xp[3];
            const float4* pp = reinterpret_cast<const float4*>(pseudo + (size_t)e * EDGE_DIM);
            float4 p0 = pp[0], p1 = pp[1];
            p[0]=p0.x; p[1]=p0.y; p[2]=p0.z; p[3]=p0.w;
            p[4]=p1.x; p[5]=p1.y; p[6]=p1.z; p[7]=p1.w;
        } else {
            float4 z = make_float4(0.f, 0.f, 0.f, 0.f);
            xd[0] = z; xd[1] = z; xd[2] = z; xd[3] = z;
            #pragma unroll
            for (int k = 0; k < EDGE_DIM; ++k) p[k] = 0.f;
        }
    }
    float b2v[16];
    {
        const float4* bp = reinterpret_cast<const float4*>(b2t + o * 16);
        #pragma unroll
        for (int c4 = 0; c4 < 4; ++c4) {
            float4 bv = bp[c4];
            b2v[c4*4+0] = bv.x; b2v[c4*4+1] = bv.y;
            b2v[c4*4+2] = bv.z; b2v[c4*4+3] = bv.w;
        }
    }

    // ---- Wl copy: 4 chunks of 4 uint4 (16 VGPR in flight max) ----
    for (int ch = 0; ch < 4; ++ch) {
        uint4 c0 = W2p[lane + (ch * 4 + 0) * 64];
        uint4 c1 = W2p[lane + (ch * 4 + 1) * 64];
        uint4 c2 = W2p[lane + (ch * 4 + 2) * 64];
        uint4 c3 = W2p[lane + (ch * 4 + 3) * 64];
        Wl[lane + (ch * 4 + 0) * 64] = c0;
        Wl[lane + (ch * 4 + 1) * 64] = c1;
        Wl[lane + (ch * 4 + 2) * 64] = c2;
        Wl[lane + (ch * 4 + 3) * 64] = c3;
    }

    // ---- MLP (k-outer: W1 rows contiguous -> wide wave-uniform scalar loads) ----
    {
        float h[HID];
        #pragma unroll
        for (int j = 0; j < HID; ++j) h[j] = b1[j];
        #pragma unroll
        for (int k = 0; k < EDGE_DIM; ++k) {
            float pk = p[k];
            const float* wr = W1 + k * HID;
            #pragma unroll
            for (int j = 0; j < HID; ++j)
                h[j] = fmaf(pk, wr[j], h[j]);
        }
        uint32_t hw[16];
        #pragma unroll
        for (int v = 0; v < 16; ++v) {
            float a0 = h[2*v]   > 0.f ? h[2*v]   : 0.f;
            float a1 = h[2*v+1] > 0.f ? h[2*v+1] : 0.f;
            hw[v] = valid ? pack_bf16(a0, a1) : 0u;
        }
        uint4* hp = reinterpret_cast<uint4*>(&Hl[t * HSTR]);
        hp[0] = make_uint4(hw[0],  hw[1],  hw[2],  hw[3]);
        hp[1] = make_uint4(hw[4],  hw[5],  hw[6],  hw[7]);
        hp[2] = make_uint4(hw[8],  hw[9],  hw[10], hw[11]);
        hp[3] = make_uint4(hw[12], hw[13], hw[14], hw[15]);
    }
    // no barrier: every wave reads only its own 64 rows of Hl/xl; Wl identical

    int ebase = w * 64;

    // ---- GEMM: all operands from LDS/regs (q-outer, macc[4] live) ----
    #pragma unroll
    for (int q = 0; q < 4; ++q) {
        short8v A = *reinterpret_cast<const short8v*>(
            &Hl[(size_t)(ebase + q * 16 + o) * HSTR + g * 4]);
        float macc[4] = {0.f, 0.f, 0.f, 0.f};
        #pragma unroll
        for (int cq = 0; cq < 4; ++cq) {
            short8v Bf[4];
            #pragma unroll
            for (int j = 0; j < 4; ++j)
                Bf[j] = *reinterpret_cast<const short8v*>(&Wl[(cq * 4 + j) * 64 + lane]);
            f32x4 C[4];
            #pragma unroll
            for (int j = 0; j < 4; ++j) {
                float bb = b2v[cq * 4 + j];
                C[j] = __builtin_amdgcn_mfma_f32_16x16x32_bf16(
                    A, Bf[j], (f32x4){bb, bb, bb, bb}, 0, 0, 0);
            }
            #pragma unroll
            for (int r = 0; r < 4; ++r) {
                int el = ebase + q * 16 + g * 4 + r;
                float4 xa = *reinterpret_cast<const float4*>(&xl[el * XSTR + cq * 4]);
                float m = macc[r];
                m = fmaf(xa.x, C[0][r], m); m = fmaf(xa.y, C[1][r], m);
                m = fmaf(xa.z, C[2][r], m); m = fmaf(xa.w, C[3][r], m);
                macc[r] = m;
            }
        }
        // bf16 pair-pack; even-o lanes store dword (o>>1) of this edge's slot
        #pragma unroll
        for (int r = 0; r < 4; ++r) {
            int el = q * 16 + g * 4 + r;               // wave-local 0..63
            int sl = __shfl(slv, el, 64);
            float other = __shfl_xor(macc[r], 1, 64);
            if (sl >= 0 && !(o & 1)) {
                uint32_t dw = pack_bf16(macc[r], other);
                msgu[(size_t)sl * 8 + (o >> 1)] = dw;
            }
        }
    }
}

// wave per node: out = bias + x@root + sum of msg rows [base, base+cnt)
__global__ __launch_bounds__(256) void nnconv_gather1(
    const uint32_t* __restrict__ msgu, const int* __restrict__ baseArr,
    const int* __restrict__ cntArr, const float* __restrict__ x,
    const float* __restrict__ root, const float* __restrict__ bias,
    float* __restrict__ out, int n_nodes)
{
    int wave = threadIdx.x >> 6, lane = threadIdx.x & 63;
    int n = blockIdx.x * 4 + wave;
    if (n >= n_nodes) return;
    int group = lane >> 4, o = lane & 15;
    int cntn = cntArr[n];
    size_t s = (size_t)baseArr[n];
    float acc = 0.f;
    int half = o & 1;
    int dwi = o >> 1;
    for (int k = group; k < cntn; k += 4) {
        uint32_t u = msgu[(s + k) * 8 + dwi];
        uint32_t h16 = half ? (u & 0xFFFF0000u) : (u << 16);
        union { uint32_t u; float f; } cv; cv.u = h16;
        acc += cv.f;
    }
    acc += __shfl_xor(acc, 16, 64);
    acc += __shfl_xor(acc, 32, 64);
    if (group == 0) {
        float r = bias[o];
        const float* xr = x + (size_t)n * IN_C;
        #pragma unroll
        for (int i = 0; i < IN_C; ++i)
            r = fmaf(xr[i], root[i * OUT_C + o], r);
        out[n * OUT_C + o] = r + acc;
    }
}

// ============ fallback: direct-atomic path ============

__global__ __launch_bounds__(256) void nnconv_init_out(
    const float* __restrict__ x, const float* __restrict__ root,
    const float* __restrict__ bias, float* __restrict__ out, int n_nodes)
{
    int t = blockIdx.x * blockDim.x + threadIdx.x;
    if (t >= n_nodes * OUT_C) return;
    int n = t >> 4, o = t & 15;
    float acc = bias[o];
    #pragma unroll
    for (int i = 0; i < IN_C; ++i)
        acc = fmaf(x[n * IN_C + i], root[i * OUT_C + o], acc);
    out[t] = acc;
}

__global__ __launch_bounds__(256) void nnconv_edge_atomic(
    const float* __restrict__ x, const int* __restrict__ edge_index,
    const float* __restrict__ pseudo,
    const float* __restrict__ W1, const float* __restrict__ b1,
    const float* __restrict__ W2, const float* __restrict__ b2,
    float* __restrict__ out, int n_edges)
{
    int e = blockIdx.x * blockDim.x + threadIdx.x;
    if (e >= n_edges) return;
    int row = edge_index[e];
    int col = edge_index[n_edges + e];
    float p[EDGE_DIM];
    const float4* pp = reinterpret_cast<const float4*>(pseudo + (size_t)e * EDGE_DIM);
    float4 p0 = pp[0], p1 = pp[1];
    p[0]=p0.x; p[1]=p0.y; p[2]=p0.z; p[3]=p0.w;
    p[4]=p1.x; p[5]=p1.y; p[6]=p1.z; p[7]=p1.w;
    float h[HID];
    #pragma unroll
    for (int j = 0; j < HID; ++j) {
        float a = b1[j];
        #pragma unroll
        for (int k = 0; k < EDGE_DIM; ++k)
            a = fmaf(p[k], W1[k * HID + j], a);
        h[j] = a > 0.f ? a : 0.f;
    }
    float xg[IN_C];
    const float4* xp = reinterpret_cast<const float4*>(x + (size_t)col * IN_C);
    #pragma unroll
    for (int q = 0; q < 4; ++q) {
        float4 v = xp[q];
        xg[q*4+0]=v.x; xg[q*4+1]=v.y; xg[q*4+2]=v.z; xg[q*4+3]=v.w;
    }
    float m[OUT_C];
    #pragma unroll
    for (int o = 0; o < OUT_C; ++o) m[o] = 0.f;
    for (int i = 0; i < IN_C; ++i) {
        float wv[OUT_C];
        const float* b2r = b2 + i * OUT_C;
        #pragma unroll
        for (int o = 0; o < OUT_C; ++o) wv[o] = b2r[o];
        #pragma unroll
        for (int j = 0; j < HID; ++j) {
            float hj = h[j];
            const float* wr = W2 + j * (IN_C * OUT_C) + i * OUT_C;
            #pragma unroll
            for (int o = 0; o < OUT_C; ++o)
                wv[o] = fmaf(hj, wr[o], wv[o]);
        }
        float xi = xg[i];
        #pragma unroll
        for (int o = 0; o < OUT_C; ++o)
            m[o] = fmaf(xi, wv[o], m[o]);
    }
    float* op = out + (size_t)row * OUT_C;
    #pragma unroll
    for (int o = 0; o < OUT_C; ++o)
        atomicAdd(op + o, m[o]);
}

// ---------------- launch ----------------

extern "C" void kernel_launch(void* const* d_in, const int* in_sizes, int n_in,
                              void* d_out, int out_size, void* d_ws, size_t ws_size,
                              hipStream_t stream) {
    const float* x      = (const float*)d_in[0];
    const int*   eidx   = (const int*)  d_in[1];
    const float* pseudo = (const float*)d_in[2];
    const float* W1     = (const float*)d_in[3];
    const float* b1     = (const float*)d_in[4];
    const float* W2     = (const float*)d_in[5];
    const float* b2     = (const float*)d_in[6];
    const float* root   = (const float*)d_in[7];
    const float* bias   = (const float*)d_in[8];
    float* out = (float*)d_out;

    int n_nodes = in_sizes[0] / IN_C;
    int n_edges = in_sizes[1] / 2;
    int eblocks128 = (n_edges + FEPB - 1) / FEPB;
    int eblocks256 = (n_edges + 255) / 256;
    int K = (n_edges + CHUNK - 1) / CHUNK;
    char* wsp = (char*)d_ws;

    // tier-1 layout: baseArr[RPAD] cntArr[RPAD] total[64] |256| W2p[1024 u4] b2t[256]
    //   |256| lrank16[Epad u16] |256| histg[K*HDW u32] | chunkbase[K*RPAD u32] | msgu[E*8 u32]
    if (n_nodes <= RPAD) {
        int* baseArr = (int*)wsp;
        int* cntArr  = baseArr + RPAD;
        int* total   = cntArr + RPAD;
        size_t off = sizeof(int) * (size_t)(2 * RPAD + 64);
        off = (off + 255) & ~(size_t)255;
        uint4* W2p = (uint4*)(wsp + off);
        off += sizeof(uint4) * 1024;
        float* b2t = (float*)(wsp + off);
        off += sizeof(float) * 256;
        off = (off + 255) & ~(size_t)255;
        uint16_t* lrank16 = (uint16_t*)(wsp + off);
        off += sizeof(uint16_t) * (size_t)eblocks128 * FEPB;
        off = (off + 255) & ~(size_t)255;
        uint32_t* histg = (uint32_t*)(wsp + off);
        off += sizeof(uint32_t) * (size_t)K * HDW;
        uint32_t* chunkbase = (uint32_t*)(wsp + off);
        off += sizeof(uint32_t) * (size_t)K * RPAD;
        uint32_t* msgu = (uint32_t*)(wsp + off);
        size_t need = off + sizeof(uint32_t) * (size_t)n_edges * 8;

        if (ws_size >= need) {
            nnconv_rank<<<K + 5, 256, 0, stream>>>(
                eidx, lrank16, histg, W2, W2p, b2, b2t, total, n_edges, K);
            nnconv_scan<<<HDW / 256, 256, 0, stream>>>(
                histg, chunkbase, baseArr, cntArr, total, K);
            nnconv_fused1<<<eblocks128, FEPB, 0, stream>>>(
                pseudo, eidx, x, W1, b1, W2p, b2t, chunkbase, lrank16, msgu, n_edges);
            nnconv_gather1<<<(n_nodes + 3) / 4, 256, 0, stream>>>(
                msgu, baseArr, cntArr, x, root, bias, out, n_nodes);
            return;
        }
    }

    nnconv_init_out<<<(n_nodes * OUT_C + 255) / 256, 256, 0, stream>>>(
        x, root, bias, out, n_nodes);
    nnconv_edge_atomic<<<eblocks256, 256, 0, stream>>>(
        x, eidx, pseudo, W1, b1, W2, b2, out, n_edges);
}

// Round 24
// 83.606 us; speedup vs baseline: 1.4518x; 1.4505x over previous
//
#include <hip/hip_runtime.h>
#include <stdint.h>
#include <limits.h>

#define IN_C   16
#define OUT_C  16
#define EDGE_DIM 8
#define HID    32
#define HSTR   20      // H LDS row stride in dwords
#define XSTR   20      // x LDS row stride in floats
#define MAXDEG 48      // fixed per-node msg capacity (max degree ~35 for E/N=16)
#define FEPB   128     // edges per tile (2 waves)
#define PBLK   1024    // persistent blocks (4 per CU)

typedef __attribute__((ext_vector_type(8))) short short8v;  // bf16x8 MFMA frag
typedef __attribute__((ext_vector_type(4))) float f32x4;

__device__ __forceinline__ uint32_t pack_bf16(float a, float b) {
    union { float f; uint32_t u; } ua, ub;
    ua.f = a; ub.f = b;
    uint32_t lo = (ua.u + 0x7FFFu + ((ua.u >> 16) & 1u)) >> 16;   // RNE
    uint32_t hi = (ub.u + 0x7FFFu + ((ub.u >> 16) & 1u)) >> 16;
    return (lo & 0xFFFFu) | (hi << 16);
}

// blocks [0,4): pre-pack W2 into per-lane MFMA B-fragments (bf16).
// blocks [4,...): grid-stride zero of cur[] and ovf[].
__global__ __launch_bounds__(256) void nnconv_prep(
    const float* __restrict__ W2, uint4* __restrict__ W2p,
    int* __restrict__ zero_base, int n_zero_ints)
{
    int bid = blockIdx.x;
    if (bid < 4) {
        int idx = bid * 256 + threadIdx.x;      // 0..1023 = ci*64 + l
        int ci = idx >> 6, l = idx & 63;
        int o = l & 15, g = l >> 4;
        uint32_t u[4];
        #pragma unroll
        for (int v = 0; v < 4; ++v) {
            int k0 = g * 8 + 2 * v;
            u[v] = pack_bf16(W2[(size_t)k0 * 256 + ci * 16 + o],
                             W2[(size_t)(k0 + 1) * 256 + ci * 16 + o]);
        }
        W2p[idx] = make_uint4(u[0], u[1], u[2], u[3]);
        return;
    }
    int t = (bid - 4) * 256 + threadIdx.x;
    int stride = (gridDim.x - 4) * 256;
    for (int i = t; i < n_zero_ints; i += stride)
        zero_base[i] = 0;
}

// ============ TIER 1: persistent fused MLP+GEMM (R19 body, grid-stride tiles) ============
// Wl (W2p copy) + b2v hoisted: paid once per block, amortized over ~4 tiles.
// Tile iterations have no barrier -> next tile's loads overlap current GEMM.
// Per-wave LDS locality (each wave owns its 64 rows of Hl/xl) -> no __syncthreads.
__global__ __launch_bounds__(256, 2) void nnconv_fused1(
    const float* __restrict__ pseudo, const int* __restrict__ eidx,
    const float* __restrict__ x,
    const float* __restrict__ W1, const float* __restrict__ b1,
    const uint4* __restrict__ W2p, const float* __restrict__ b2,
    int* __restrict__ cur, float* __restrict__ ovf,
    float* __restrict__ msg, int n_edges, int ntiles)
{
    __shared__ uint32_t Hl[FEPB * HSTR];
    __shared__ float    xl[FEPB * XSTR];
    __shared__ uint4    Wl[1024];            // 16 KB block-shared B-fragments

    int t = threadIdx.x;
    int lane = t & 63, w = t >> 6;
    int o = lane & 15, g = lane >> 4;
    int ebase = w * 64;

    // ---- hoisted: Wl copy (4 chunks of 4 uint4) + b2v ----
    for (int ch = 0; ch < 4; ++ch) {
        uint4 c0 = W2p[lane + (ch * 4 + 0) * 64];
        uint4 c1 = W2p[lane + (ch * 4 + 1) * 64];
        uint4 c2 = W2p[lane + (ch * 4 + 2) * 64];
        uint4 c3 = W2p[lane + (ch * 4 + 3) * 64];
        Wl[lane + (ch * 4 + 0) * 64] = c0;
        Wl[lane + (ch * 4 + 1) * 64] = c1;
        Wl[lane + (ch * 4 + 2) * 64] = c2;
        Wl[lane + (ch * 4 + 3) * 64] = c3;
    }
    float b2v[16];
    #pragma unroll
    for (int ci = 0; ci < 16; ++ci) b2v[ci] = b2[ci * 16 + o];

    for (int tb = blockIdx.x; tb < ntiles; tb += gridDim.x) {
        int e0 = tb * FEPB;
        int e  = e0 + t;
        bool valid = e < n_edges;

        // ---- stage: x + pseudo loads ----
        int row = 0;
        float p[EDGE_DIM];
        {
            float4* xd = reinterpret_cast<float4*>(&xl[t * XSTR]);
            if (valid) {
                row = eidx[e];
                int c = eidx[n_edges + e];
                const float4* xp = reinterpret_cast<const float4*>(x + (size_t)c * IN_C);
                xd[0] = xp[0]; xd[1] = xp[1]; xd[2] = xp[2]; xd[3] = xp[3];
                const float4* pp = reinterpret_cast<const float4*>(pseudo + (size_t)e * EDGE_DIM);
                float4 p0 = pp[0], p1 = pp[1];
                p[0]=p0.x; p[1]=p0.y; p[2]=p0.z; p[3]=p0.w;
                p[4]=p1.x; p[5]=p1.y; p[6]=p1.z; p[7]=p1.w;
            } else {
                float4 z = make_float4(0.f, 0.f, 0.f, 0.f);
                xd[0] = z; xd[1] = z; xd[2] = z; xd[3] = z;
                #pragma unroll
                for (int k = 0; k < EDGE_DIM; ++k) p[k] = 0.f;
            }
        }

        // ---- MLP (k-outer: W1 rows contiguous -> wide wave-uniform scalar loads) ----
        {
            float h[HID];
            #pragma unroll
            for (int j = 0; j < HID; ++j) h[j] = b1[j];
            #pragma unroll
            for (int k = 0; k < EDGE_DIM; ++k) {
                float pk = p[k];
                const float* wr = W1 + k * HID;
                #pragma unroll
                for (int j = 0; j < HID; ++j)
                    h[j] = fmaf(pk, wr[j], h[j]);
            }
            uint32_t hw[16];
            #pragma unroll
            for (int v = 0; v < 16; ++v) {
                float a0 = h[2*v]   > 0.f ? h[2*v]   : 0.f;
                float a1 = h[2*v+1] > 0.f ? h[2*v+1] : 0.f;
                hw[v] = valid ? pack_bf16(a0, a1) : 0u;
            }
            uint4* hp = reinterpret_cast<uint4*>(&Hl[t * HSTR]);
            hp[0] = make_uint4(hw[0],  hw[1],  hw[2],  hw[3]);
            hp[1] = make_uint4(hw[4],  hw[5],  hw[6],  hw[7]);
            hp[2] = make_uint4(hw[8],  hw[9],  hw[10], hw[11]);
            hp[3] = make_uint4(hw[12], hw[13], hw[14], hw[15]);
        }
        // no barrier: wave-local Hl/xl; in-order DS pipe per wave

        // ---- rank atomic: issued post-MLP; consumed at stores (hides under GEMM) ----
        int slv = INT_MIN;
        if (valid) {
            int rank = atomicAdd(&cur[row], 1);
            slv = (rank < MAXDEG) ? (row * MAXDEG + rank) : (-row - 1);
        }

        // ---- GEMM: all operands from LDS/regs (q-outer, macc[4] live) ----
        #pragma unroll
        for (int q = 0; q < 4; ++q) {
            short8v A = *reinterpret_cast<const short8v*>(
                &Hl[(size_t)(ebase + q * 16 + o) * HSTR + g * 4]);
            float macc[4] = {0.f, 0.f, 0.f, 0.f};
            #pragma unroll
            for (int cq = 0; cq < 4; ++cq) {
                short8v Bf[4];
                #pragma unroll
                for (int j = 0; j < 4; ++j)
                    Bf[j] = *reinterpret_cast<const short8v*>(&Wl[(cq * 4 + j) * 64 + lane]);
                f32x4 C[4];
                #pragma unroll
                for (int j = 0; j < 4; ++j) {
                    float bb = b2v[cq * 4 + j];
                    C[j] = __builtin_amdgcn_mfma_f32_16x16x32_bf16(
                        A, Bf[j], (f32x4){bb, bb, bb, bb}, 0, 0, 0);
                }
                #pragma unroll
                for (int r = 0; r < 4; ++r) {
                    int el = ebase + q * 16 + g * 4 + r;
                    float4 xa = *reinterpret_cast<const float4*>(&xl[el * XSTR + cq * 4]);
                    float m = macc[r];
                    m = fmaf(xa.x, C[0][r], m); m = fmaf(xa.y, C[1][r], m);
                    m = fmaf(xa.z, C[2][r], m); m = fmaf(xa.w, C[3][r], m);
                    macc[r] = m;
                }
            }
            #pragma unroll
            for (int r = 0; r < 4; ++r) {
                int el = q * 16 + g * 4 + r;               // wave-local 0..63
                int sl = __shfl(slv, el, 64);
                if (sl >= 0)
                    msg[(size_t)sl * OUT_C + o] = macc[r];
                else if (sl != INT_MIN)
                    atomicAdd(&ovf[(size_t)(-sl - 1) * OUT_C + o], macc[r]);
            }
        }
    }
}

// wave per node: out = bias + x@root + sum msg rows + ovf
__global__ __launch_bounds__(256) void nnconv_gather1(
    const float* __restrict__ msg, const int* __restrict__ cur,
    const float* __restrict__ ovf, const float* __restrict__ x,
    const float* __restrict__ root, const float* __restrict__ bias,
    float* __restrict__ out, int n_nodes)
{
    int wave = threadIdx.x >> 6, lane = threadIdx.x & 63;
    int n = blockIdx.x * 4 + wave;
    if (n >= n_nodes) return;
    int group = lane >> 4, o = lane & 15;
    int cntn = cur[n]; if (cntn > MAXDEG) cntn = MAXDEG;
    size_t s = (size_t)n * MAXDEG;
    float acc = 0.f;
    for (int k = group; k < cntn; k += 4)
        acc += msg[(s + k) * OUT_C + o];
    acc += __shfl_xor(acc, 16, 64);
    acc += __shfl_xor(acc, 32, 64);
    if (group == 0) {
        float r = bias[o] + ovf[(size_t)n * OUT_C + o];
        const float* xr = x + (size_t)n * IN_C;
        #pragma unroll
        for (int i = 0; i < IN_C; ++i)
            r = fmaf(xr[i], root[i * OUT_C + o], r);
        out[n * OUT_C + o] = r + acc;
    }
}

// ============ TIER 3: direct-atomic fallback ============

__global__ __launch_bounds__(256) void nnconv_init_out(
    const float* __restrict__ x, const float* __restrict__ root,
    const float* __restrict__ bias, float* __restrict__ out, int n_nodes)
{
    int t = blockIdx.x * blockDim.x + threadIdx.x;
    if (t >= n_nodes * OUT_C) return;
    int n = t >> 4, o = t & 15;
    float acc = bias[o];
    #pragma unroll
    for (int i = 0; i < IN_C; ++i)
        acc = fmaf(x[n * IN_C + i], root[i * OUT_C + o], acc);
    out[t] = acc;
}

__global__ __launch_bounds__(256) void nnconv_edge_atomic(
    const float* __restrict__ x, const int* __restrict__ edge_index,
    const float* __restrict__ pseudo,
    const float* __restrict__ W1, const float* __restrict__ b1,
    const float* __restrict__ W2, const float* __restrict__ b2,
    float* __restrict__ out, int n_edges)
{
    int e = blockIdx.x * blockDim.x + threadIdx.x;
    if (e >= n_edges) return;
    int row = edge_index[e];
    int col = edge_index[n_edges + e];
    float p[EDGE_DIM];
    const float4* pp = reinterpret_cast<const float4*>(pseudo + (size_t)e * EDGE_DIM);
    float4 p0 = pp[0], p1 = pp[1];
    p[0]=p0.x; p[1]=p0.y; p[2]=p0.z; p[3]=p0.w;
    p[4]=p1.x; p[5]=p1.y; p[6]=p1.z; p[7]=p1.w;
    float h[HID];
    #pragma unroll
    for (int j = 0; j < HID; ++j) {
        float a = b1[j];
        #pragma unroll
        for (int k = 0; k < EDGE_DIM; ++k)
            a = fmaf(p[k], W1[k * HID + j], a);
        h[j] = a > 0.f ? a : 0.f;
    }
    float xg[IN_C];
    const float4* xp = reinterpret_cast<const float4*>(x + (size_t)col * IN_C);
    #pragma unroll
    for (int q = 0; q < 4; ++q) {
        float4 v = xp[q];
        xg[q*4+0]=v.x; xg[q*4+1]=v.y; xg[q*4+2]=v.z; xg[q*4+3]=v.w;
    }
    float m[OUT_C];
    #pragma unroll
    for (int o = 0; o < OUT_C; ++o) m[o] = 0.f;
    for (int i = 0; i < IN_C; ++i) {
        float wv[OUT_C];
        const float* b2r = b2 + i * OUT_C;
        #pragma unroll
        for (int o = 0; o < OUT_C; ++o) wv[o] = b2r[o];
        #pragma unroll
        for (int j = 0; j < HID; ++j) {
            float hj = h[j];
            const float* wr = W2 + j * (IN_C * OUT_C) + i * OUT_C;
            #pragma unroll
            for (int o = 0; o < OUT_C; ++o)
                wv[o] = fmaf(hj, wr[o], wv[o]);
        }
        float xi = xg[i];
        #pragma unroll
        for (int o = 0; o < OUT_C; ++o)
            m[o] = fmaf(xi, wv[o], m[o]);
    }
    float* op = out + (size_t)row * OUT_C;
    #pragma unroll
    for (int o = 0; o < OUT_C; ++o)
        atomicAdd(op + o, m[o]);
}

// ---------------- launch ----------------

extern "C" void kernel_launch(void* const* d_in, const int* in_sizes, int n_in,
                              void* d_out, int out_size, void* d_ws, size_t ws_size,
                              hipStream_t stream) {
    const float* x      = (const float*)d_in[0];
    const int*   eidx   = (const int*)  d_in[1];
    const float* pseudo = (const float*)d_in[2];
    const float* W1     = (const float*)d_in[3];
    const float* b1     = (const float*)d_in[4];
    const float* W2     = (const float*)d_in[5];
    const float* b2     = (const float*)d_in[6];
    const float* root   = (const float*)d_in[7];
    const float* bias   = (const float*)d_in[8];
    float* out = (float*)d_out;

    int n_nodes = in_sizes[0] / IN_C;
    int n_edges = in_sizes[1] / 2;
    int ntiles  = (n_edges + FEPB - 1) / FEPB;
    int eblocks256 = (n_edges + 255) / 256;
    char* wsp = (char*)d_ws;

    // tier 1 layout: cur[N] ovf[N*16 f32] |256| W2p[1024 u4] |256| msg[N*MAXDEG*16]
    {
        int* cur1  = (int*)wsp;
        float* ovf = (float*)(cur1 + n_nodes);
        size_t off = sizeof(int) * (size_t)n_nodes + sizeof(float) * (size_t)n_nodes * OUT_C;
        off = (off + 255) & ~(size_t)255;
        uint4* W2p = (uint4*)(wsp + off);
        off += sizeof(uint4) * 1024;
        off = (off + 255) & ~(size_t)255;
        float* msg = (float*)(wsp + off);
        size_t need = off + sizeof(float) * (size_t)n_nodes * MAXDEG * OUT_C;

        if (ws_size >= need) {
            int n_zero_ints = n_nodes + n_nodes * OUT_C;   // cur + ovf (contiguous)
            nnconv_prep<<<4 + 64, 256, 0, stream>>>(W2, W2p, cur1, n_zero_ints);
            int grid = ntiles < PBLK ? ntiles : PBLK;
            nnconv_fused1<<<grid, FEPB, 0, stream>>>(
                pseudo, eidx, x, W1, b1, W2p, b2, cur1, ovf, msg, n_edges, ntiles);
            nnconv_gather1<<<(n_nodes + 3) / 4, 256, 0, stream>>>(
                msg, cur1, ovf, x, root, bias, out, n_nodes);
            return;
        }
    }

    nnconv_init_out<<<(n_nodes * OUT_C + 255) / 256, 256, 0, stream>>>(
        x, root, bias, out, n_nodes);
    nnconv_edge_atomic<<<eblocks256, 256, 0, stream>>>(
        x, eidx, pseudo, W1, b1, W2, b2, out, n_edges);
}

// Round 25
// 76.529 us; speedup vs baseline: 1.5860x; 1.0925x over previous
//
#include <hip/hip_runtime.h>
#include <stdint.h>
#include <limits.h>

#define IN_C   16
#define OUT_C  16
#define EDGE_DIM 8
#define HID    32
#define HSTR   20      // H LDS row stride in dwords
#define XSTR   20      // x LDS row stride in floats
#define MAXDEG 48      // fixed per-node msg capacity (max degree ~35 for E/N=16)
#define FEPB   128     // edges per fused block (2 waves)

typedef __attribute__((ext_vector_type(8))) short short8v;  // bf16x8 MFMA frag
typedef __attribute__((ext_vector_type(4))) float f32x4;

__device__ __forceinline__ uint32_t pack_bf16(float a, float b) {
    union { float f; uint32_t u; } ua, ub;
    ua.f = a; ub.f = b;
    uint32_t lo = (ua.u + 0x7FFFu + ((ua.u >> 16) & 1u)) >> 16;   // RNE
    uint32_t hi = (ub.u + 0x7FFFu + ((ub.u >> 16) & 1u)) >> 16;
    return (lo & 0xFFFFu) | (hi << 16);
}

// blocks [0,4): pre-pack W2 into per-lane MFMA B-fragments (bf16).
// blocks [4,...): grid-stride zero of cur[] and ovf[].
__global__ __launch_bounds__(256) void nnconv_prep(
    const float* __restrict__ W2, uint4* __restrict__ W2p,
    int* __restrict__ zero_base, int n_zero_ints)
{
    int bid = blockIdx.x;
    if (bid < 4) {
        int idx = bid * 256 + threadIdx.x;      // 0..1023 = ci*64 + l
        int ci = idx >> 6, l = idx & 63;
        int o = l & 15, g = l >> 4;
        uint32_t u[4];
        #pragma unroll
        for (int v = 0; v < 4; ++v) {
            int k0 = g * 8 + 2 * v;
            u[v] = pack_bf16(W2[(size_t)k0 * 256 + ci * 16 + o],
                             W2[(size_t)(k0 + 1) * 256 + ci * 16 + o]);
        }
        W2p[idx] = make_uint4(u[0], u[1], u[2], u[3]);
        return;
    }
    int t = (bid - 4) * 256 + threadIdx.x;
    int stride = (gridDim.x - 4) * 256;
    for (int i = t; i < n_zero_ints; i += stride)
        zero_base[i] = 0;
}

// ============ TIER 1: fused MLP+GEMM; LDS-resident W2p; atomic post-MLP ============
// R19 configuration (best measured: fused ~60us, total 76.3us).
// q-outer / macc[4] / per-q scatter keeps ~100 VGPR under the (256,2)=128 cap.
// Wl copied in 4-uint4 chunks BEFORE the MLP (temps die before h[32] lives);
// each wave writes the full table redundantly (identical values -> benign race,
// no barrier). Rank atomic issued AFTER all vmem loads: no vmem op exists
// between it and its first consume (q0 store) -> round-trip hides under GEMM.
__global__ __launch_bounds__(256, 2) void nnconv_fused1(
    const float* __restrict__ pseudo, const int* __restrict__ eidx,
    const float* __restrict__ x,
    const float* __restrict__ W1, const float* __restrict__ b1,
    const uint4* __restrict__ W2p, const float* __restrict__ b2,
    int* __restrict__ cur, float* __restrict__ ovf,
    float* __restrict__ msg, int n_edges)
{
    __shared__ uint32_t Hl[FEPB * HSTR];
    __shared__ float    xl[FEPB * XSTR];
    __shared__ uint4    Wl[1024];            // 16 KB block-shared B-fragments

    int t  = threadIdx.x;
    int e0 = blockIdx.x * FEPB;
    int e  = e0 + t;
    bool valid = e < n_edges;
    int lane = t & 63, w = t >> 6;
    int o = lane & 15, g = lane >> 4;

    // ---- stage: x + pseudo + b2 loads ----
    int row = 0;
    float p[EDGE_DIM];
    {
        float4* xd = reinterpret_cast<float4*>(&xl[t * XSTR]);
        if (valid) {
            row = eidx[e];
            int c = eidx[n_edges + e];
            const float4* xp = reinterpret_cast<const float4*>(x + (size_t)c * IN_C);
            xd[0] = xp[0]; xd[1] = xp[1]; xd[2] = xp[2]; xd[3] = xp[3];
            const float4* pp = reinterpret_cast<const float4*>(pseudo + (size_t)e * EDGE_DIM);
            float4 p0 = pp[0], p1 = pp[1];
            p[0]=p0.x; p[1]=p0.y; p[2]=p0.z; p[3]=p0.w;
            p[4]=p1.x; p[5]=p1.y; p[6]=p1.z; p[7]=p1.w;
        } else {
            float4 z = make_float4(0.f, 0.f, 0.f, 0.f);
            xd[0] = z; xd[1] = z; xd[2] = z; xd[3] = z;
            #pragma unroll
            for (int k = 0; k < EDGE_DIM; ++k) p[k] = 0.f;
        }
    }
    float b2v[16];
    #pragma unroll
    for (int ci = 0; ci < 16; ++ci) b2v[ci] = b2[ci * 16 + o];

    // ---- Wl copy: 4 chunks of 4 uint4 (16 VGPR in flight max) ----
    for (int ch = 0; ch < 4; ++ch) {
        uint4 c0 = W2p[lane + (ch * 4 + 0) * 64];
        uint4 c1 = W2p[lane + (ch * 4 + 1) * 64];
        uint4 c2 = W2p[lane + (ch * 4 + 2) * 64];
        uint4 c3 = W2p[lane + (ch * 4 + 3) * 64];
        Wl[lane + (ch * 4 + 0) * 64] = c0;
        Wl[lane + (ch * 4 + 1) * 64] = c1;
        Wl[lane + (ch * 4 + 2) * 64] = c2;
        Wl[lane + (ch * 4 + 3) * 64] = c3;
    }

    // ---- MLP (k-outer: W1 rows contiguous -> wide wave-uniform scalar loads) ----
    {
        float h[HID];
        #pragma unroll
        for (int j = 0; j < HID; ++j) h[j] = b1[j];
        #pragma unroll
        for (int k = 0; k < EDGE_DIM; ++k) {
            float pk = p[k];
            const float* wr = W1 + k * HID;
            #pragma unroll
            for (int j = 0; j < HID; ++j)
                h[j] = fmaf(pk, wr[j], h[j]);
        }
        uint32_t hw[16];
        #pragma unroll
        for (int v = 0; v < 16; ++v) {
            float a0 = h[2*v]   > 0.f ? h[2*v]   : 0.f;
            float a1 = h[2*v+1] > 0.f ? h[2*v+1] : 0.f;
            hw[v] = valid ? pack_bf16(a0, a1) : 0u;
        }
        uint4* hp = reinterpret_cast<uint4*>(&Hl[t * HSTR]);
        hp[0] = make_uint4(hw[0],  hw[1],  hw[2],  hw[3]);
        hp[1] = make_uint4(hw[4],  hw[5],  hw[6],  hw[7]);
        hp[2] = make_uint4(hw[8],  hw[9],  hw[10], hw[11]);
        hp[3] = make_uint4(hw[12], hw[13], hw[14], hw[15]);
    }
    // no barrier: every wave reads only its own 64 rows of Hl/xl; Wl identical

    // ---- rank atomic: last vmem op before the q0-store consume ----
    int slv = INT_MIN;
    if (valid) {
        int rank = atomicAdd(&cur[row], 1);
        slv = (rank < MAXDEG) ? (row * MAXDEG + rank) : (-row - 1);
    }

    int ebase = w * 64;

    // ---- GEMM: all operands from LDS/regs (q-outer, macc[4] live) ----
    #pragma unroll
    for (int q = 0; q < 4; ++q) {
        short8v A = *reinterpret_cast<const short8v*>(
            &Hl[(size_t)(ebase + q * 16 + o) * HSTR + g * 4]);
        float macc[4] = {0.f, 0.f, 0.f, 0.f};
        #pragma unroll
        for (int cq = 0; cq < 4; ++cq) {
            short8v Bf[4];
            #pragma unroll
            for (int j = 0; j < 4; ++j)
                Bf[j] = *reinterpret_cast<const short8v*>(&Wl[(cq * 4 + j) * 64 + lane]);
            f32x4 C[4];
            #pragma unroll
            for (int j = 0; j < 4; ++j) {
                float bb = b2v[cq * 4 + j];
                C[j] = __builtin_amdgcn_mfma_f32_16x16x32_bf16(
                    A, Bf[j], (f32x4){bb, bb, bb, bb}, 0, 0, 0);
            }
            #pragma unroll
            for (int r = 0; r < 4; ++r) {
                int el = ebase + q * 16 + g * 4 + r;
                float4 xa = *reinterpret_cast<const float4*>(&xl[el * XSTR + cq * 4]);
                float m = macc[r];
                m = fmaf(xa.x, C[0][r], m); m = fmaf(xa.y, C[1][r], m);
                m = fmaf(xa.z, C[2][r], m); m = fmaf(xa.w, C[3][r], m);
                macc[r] = m;
            }
        }
        #pragma unroll
        for (int r = 0; r < 4; ++r) {
            int el = q * 16 + g * 4 + r;               // wave-local 0..63
            int sl = __shfl(slv, el, 64);
            if (sl >= 0)
                msg[(size_t)sl * OUT_C + o] = macc[r];
            else if (sl != INT_MIN)
                atomicAdd(&ovf[(size_t)(-sl - 1) * OUT_C + o], macc[r]);
        }
    }
}

// wave per node: out = bias + x@root + sum msg rows + ovf
__global__ __launch_bounds__(256) void nnconv_gather1(
    const float* __restrict__ msg, const int* __restrict__ cur,
    const float* __restrict__ ovf, const float* __restrict__ x,
    const float* __restrict__ root, const float* __restrict__ bias,
    float* __restrict__ out, int n_nodes)
{
    int wave = threadIdx.x >> 6, lane = threadIdx.x & 63;
    int n = blockIdx.x * 4 + wave;
    if (n >= n_nodes) return;
    int group = lane >> 4, o = lane & 15;
    int cntn = cur[n]; if (cntn > MAXDEG) cntn = MAXDEG;
    size_t s = (size_t)n * MAXDEG;
    float acc = 0.f;
    for (int k = group; k < cntn; k += 4)
        acc += msg[(s + k) * OUT_C + o];
    acc += __shfl_xor(acc, 16, 64);
    acc += __shfl_xor(acc, 32, 64);
    if (group == 0) {
        float r = bias[o] + ovf[(size_t)n * OUT_C + o];
        const float* xr = x + (size_t)n * IN_C;
        #pragma unroll
        for (int i = 0; i < IN_C; ++i)
            r = fmaf(xr[i], root[i * OUT_C + o], r);
        out[n * OUT_C + o] = r + acc;
    }
}

// ============ TIER 3: direct-atomic fallback ============

__global__ __launch_bounds__(256) void nnconv_init_out(
    const float* __restrict__ x, const float* __restrict__ root,
    const float* __restrict__ bias, float* __restrict__ out, int n_nodes)
{
    int t = blockIdx.x * blockDim.x + threadIdx.x;
    if (t >= n_nodes * OUT_C) return;
    int n = t >> 4, o = t & 15;
    float acc = bias[o];
    #pragma unroll
    for (int i = 0; i < IN_C; ++i)
        acc = fmaf(x[n * IN_C + i], root[i * OUT_C + o], acc);
    out[t] = acc;
}

__global__ __launch_bounds__(256) void nnconv_edge_atomic(
    const float* __restrict__ x, const int* __restrict__ edge_index,
    const float* __restrict__ pseudo,
    const float* __restrict__ W1, const float* __restrict__ b1,
    const float* __restrict__ W2, const float* __restrict__ b2,
    float* __restrict__ out, int n_edges)
{
    int e = blockIdx.x * blockDim.x + threadIdx.x;
    if (e >= n_edges) return;
    int row = edge_index[e];
    int col = edge_index[n_edges + e];
    float p[EDGE_DIM];
    const float4* pp = reinterpret_cast<const float4*>(pseudo + (size_t)e * EDGE_DIM);
    float4 p0 = pp[0], p1 = pp[1];
    p[0]=p0.x; p[1]=p0.y; p[2]=p0.z; p[3]=p0.w;
    p[4]=p1.x; p[5]=p1.y; p[6]=p1.z; p[7]=p1.w;
    float h[HID];
    #pragma unroll
    for (int j = 0; j < HID; ++j) {
        float a = b1[j];
        #pragma unroll
        for (int k = 0; k < EDGE_DIM; ++k)
            a = fmaf(p[k], W1[k * HID + j], a);
        h[j] = a > 0.f ? a : 0.f;
    }
    float xg[IN_C];
    const float4* xp = reinterpret_cast<const float4*>(x + (size_t)col * IN_C);
    #pragma unroll
    for (int q = 0; q < 4; ++q) {
        float4 v = xp[q];
        xg[q*4+0]=v.x; xg[q*4+1]=v.y; xg[q*4+2]=v.z; xg[q*4+3]=v.w;
    }
    float m[OUT_C];
    #pragma unroll
    for (int o = 0; o < OUT_C; ++o) m[o] = 0.f;
    for (int i = 0; i < IN_C; ++i) {
        float wv[OUT_C];
        const float* b2r = b2 + i * OUT_C;
        #pragma unroll
        for (int o = 0; o < OUT_C; ++o) wv[o] = b2r[o];
        #pragma unroll
        for (int j = 0; j < HID; ++j) {
            float hj = h[j];
            const float* wr = W2 + j * (IN_C * OUT_C) + i * OUT_C;
            #pragma unroll
            for (int o = 0; o < OUT_C; ++o)
                wv[o] = fmaf(hj, wr[o], wv[o]);
        }
        float xi = xg[i];
        #pragma unroll
        for (int o = 0; o < OUT_C; ++o)
            m[o] = fmaf(xi, wv[o], m[o]);
    }
    float* op = out + (size_t)row * OUT_C;
    #pragma unroll
    for (int o = 0; o < OUT_C; ++o)
        atomicAdd(op + o, m[o]);
}

// ---------------- launch ----------------

extern "C" void kernel_launch(void* const* d_in, const int* in_sizes, int n_in,
                              void* d_out, int out_size, void* d_ws, size_t ws_size,
                              hipStream_t stream) {
    const float* x      = (const float*)d_in[0];
    const int*   eidx   = (const int*)  d_in[1];
    const float* pseudo = (const float*)d_in[2];
    const float* W1     = (const float*)d_in[3];
    const float* b1     = (const float*)d_in[4];
    const float* W2     = (const float*)d_in[5];
    const float* b2     = (const float*)d_in[6];
    const float* root   = (const float*)d_in[7];
    const float* bias   = (const float*)d_in[8];
    float* out = (float*)d_out;

    int n_nodes = in_sizes[0] / IN_C;
    int n_edges = in_sizes[1] / 2;
    int eblocks256 = (n_edges + 255) / 256;
    char* wsp = (char*)d_ws;

    // ---- tier 1 layout: cur[N] ovf[N*16 f32] |256| W2p[1024 u4] |256| msg[N*MAXDEG*16] ----
    {
        int* cur1  = (int*)wsp;
        float* ovf = (float*)(cur1 + n_nodes);
        size_t off = sizeof(int) * (size_t)n_nodes + sizeof(float) * (size_t)n_nodes * OUT_C;
        off = (off + 255) & ~(size_t)255;
        uint4* W2p = (uint4*)(wsp + off);
        off += sizeof(uint4) * 1024;
        off = (off + 255) & ~(size_t)255;
        float* msg = (float*)(wsp + off);
        size_t need = off + sizeof(float) * (size_t)n_nodes * MAXDEG * OUT_C;

        if (ws_size >= need) {
            int n_zero_ints = n_nodes + n_nodes * OUT_C;   // cur + ovf (contiguous)
            nnconv_prep<<<4 + 64, 256, 0, stream>>>(W2, W2p, cur1, n_zero_ints);
            nnconv_fused1<<<(n_edges + FEPB - 1) / FEPB, FEPB, 0, stream>>>(
                pseudo, eidx, x, W1, b1, W2p, b2, cur1, ovf, msg, n_edges);
            nnconv_gather1<<<(n_nodes + 3) / 4, 256, 0, stream>>>(
                msg, cur1, ovf, x, root, bias, out, n_nodes);
            return;
        }
    }

    nnconv_init_out<<<(n_nodes * OUT_C + 255) / 256, 256, 0, stream>>>(
        x, root, bias, out, n_nodes);
    nnconv_edge_atomic<<<eblocks256, 256, 0, stream>>>(
        x, eidx, pseudo, W1, b1, W2, b2, out, n_edges);
}